// Round 9
// baseline (2124.905 us; speedup 1.0000x reference)
//
#include <hip/hip_runtime.h>

typedef unsigned short u16;

#define NWG 256
#define NT  256
#define TS  512
#define HD  1024
#define BS  128
#define NI  64
#define NO  64
#define XR  16      // batch rows per XCD
#define CC  32      // hidden cols per CU
#define MBL 16      // u32 words per (consumer,kg) poll line (64B)

typedef __attribute__((ext_vector_type(8))) short bf16x8;
typedef __attribute__((ext_vector_type(4))) float f32x4;

__device__ __forceinline__ float bf2f(u16 u) {
    union { unsigned int i; float f; } v; v.i = ((unsigned int)u) << 16; return v.f;
}
__device__ __forceinline__ u16 f2bf(float f) {
    union { float fl; unsigned int i; } v; v.fl = f;
    unsigned int x = v.i;
    return (u16)((x + 0x7fffu + ((x >> 16) & 1u)) >> 16);  // RNE, finite inputs
}
__device__ __forceinline__ float ldv(const void* p, size_t i, bool isf32) {
    return isf32 ? ((const float*)p)[i] : bf2f(((const u16*)p)[i]);
}

// Transport (R2-proven, kept byte-for-byte): atomic publish + atomic poll.
// R3: polls MUST be atomics. R1: plain-store publish + atomic poll bounces to
// HBM. R5: flag-op count is the currency. R8: bank layout of polls is
// irrelevant (cost == memory-side RTT regardless).
__device__ __forceinline__ unsigned l2_atomic_add(unsigned* p, unsigned v) {
    unsigned old;
    asm volatile("global_atomic_add %0, %1, %2, off sc0\n\t"
                 "s_waitcnt vmcnt(0)"
                 : "=&v"(old) : "v"(p), "v"(v) : "memory");
    return old;
}
__device__ __forceinline__ void l2_atomic_swap_nr(unsigned* p, unsigned v) {
    asm volatile("global_atomic_swap %0, %1, off" :: "v"(p), "v"(v) : "memory");
}

// 8 A-fragments via sc0 loads (L1 bypass -> XCD L2). Proven data path.
__device__ __forceinline__ void load_a_frags(const u16* ap, bf16x8* a) {
    asm volatile(
        "global_load_dwordx4 %0, %8, off sc0\n\t"
        "global_load_dwordx4 %1, %8, off offset:64 sc0\n\t"
        "global_load_dwordx4 %2, %8, off offset:128 sc0\n\t"
        "global_load_dwordx4 %3, %8, off offset:192 sc0\n\t"
        "global_load_dwordx4 %4, %8, off offset:256 sc0\n\t"
        "global_load_dwordx4 %5, %8, off offset:320 sc0\n\t"
        "global_load_dwordx4 %6, %8, off offset:384 sc0\n\t"
        "global_load_dwordx4 %7, %8, off offset:448 sc0\n\t"
        "s_waitcnt vmcnt(0)"
        : "=&v"(a[0]), "=&v"(a[1]), "=&v"(a[2]), "=&v"(a[3]),
          "=&v"(a[4]), "=&v"(a[5]), "=&v"(a[6]), "=&v"(a[7])
        : "v"(ap) : "memory");
}
// 16 A-fragments (one K-half = 512 cols), single vmcnt.
__device__ __forceinline__ void load_a16(const u16* ap, bf16x8* a) {
    asm volatile(
        "global_load_dwordx4 %0, %16, off sc0\n\t"
        "global_load_dwordx4 %1, %16, off offset:64 sc0\n\t"
        "global_load_dwordx4 %2, %16, off offset:128 sc0\n\t"
        "global_load_dwordx4 %3, %16, off offset:192 sc0\n\t"
        "global_load_dwordx4 %4, %16, off offset:256 sc0\n\t"
        "global_load_dwordx4 %5, %16, off offset:320 sc0\n\t"
        "global_load_dwordx4 %6, %16, off offset:384 sc0\n\t"
        "global_load_dwordx4 %7, %16, off offset:448 sc0\n\t"
        "global_load_dwordx4 %8, %16, off offset:512 sc0\n\t"
        "global_load_dwordx4 %9, %16, off offset:576 sc0\n\t"
        "global_load_dwordx4 %10, %16, off offset:640 sc0\n\t"
        "global_load_dwordx4 %11, %16, off offset:704 sc0\n\t"
        "global_load_dwordx4 %12, %16, off offset:768 sc0\n\t"
        "global_load_dwordx4 %13, %16, off offset:832 sc0\n\t"
        "global_load_dwordx4 %14, %16, off offset:896 sc0\n\t"
        "global_load_dwordx4 %15, %16, off offset:960 sc0\n\t"
        "s_waitcnt vmcnt(0)"
        : "=&v"(a[0]), "=&v"(a[1]), "=&v"(a[2]), "=&v"(a[3]),
          "=&v"(a[4]), "=&v"(a[5]), "=&v"(a[6]), "=&v"(a[7]),
          "=&v"(a[8]), "=&v"(a[9]), "=&v"(a[10]), "=&v"(a[11]),
          "=&v"(a[12]), "=&v"(a[13]), "=&v"(a[14]), "=&v"(a[15])
        : "v"(ap) : "memory");
}

// ROUND-9 STRUCTURE: wave (kg,cg) = K-half kg (0=low,1=high) x col-half cg.
// Waves 0,1 (kg0) = FRONT: compute K-low partials (incl enc), write to LDS,
// run ahead (their next poll is issued while peers publish). Waves 2,3 (kg1)
// = BACK: K-high in registers + front partial from LDS -> elementwise in-reg
// -> h store -> drain -> LDS 2-join -> last back wave publishes 32 swaps.
// ONE __syncthreads per step; no redC reduction; no barrier2.
// Mailbox: mb[xcd][consumer(32)][kg(2)] = one 64B line of 16 producer words.
//   Front waves poll line kg0 (producers 0..15), backs kg1 (16..31).
//   Producer slot s swaps (t+1) into mb[c][s>>4][s&15] for all c: 32 swaps/CU.
// WAR (2-buffer h ping-pong): back stores h_{t+1} after barrier(t) => all 4
// waves passed poll(t): union covers all 32 CUs' flags >= t+1; flag t+1 from
// CU X => X's publish(t-1) => X's barrier(t-1) => ALL X waves done reading
// h_{t-1}. Overwriting h_{t-1} is safe. (Same induction as R2, re-derived.)

__global__ __launch_bounds__(NT)
void arnn_xcd(const void* __restrict__ xv,
              const void* __restrict__ encwv,
              const void* __restrict__ encbv,
              const void* __restrict__ recwv,
              const void* __restrict__ fgtwv,
              const void* __restrict__ decwv,
              const void* __restrict__ decbv,
              const void* __restrict__ hinitwv,
              const void* __restrict__ hinitbv,
              void* __restrict__ outv,
              u16* __restrict__ h0buf,
              u16* __restrict__ h1buf,
              unsigned* __restrict__ tickets,
              unsigned* __restrict__ mboxes)
{
    __shared__ short WB[68 * 64 * 8];          // 69632 B (2-pass staging, R4-proven)
    __shared__ float recP[2][2][16][16];       // 8192 B: [pp][cg][row][col] K-low rec+enc partial
    __shared__ float fgtP[2][2][16][16];       // 8192 B: K-low fgt partial
    __shared__ float decP[2][4][16][16];       // 8192 B: [pp][kq][row][col] dec partials
    __shared__ float decbS[16];
    __shared__ unsigned s_xcd, s_slot, jc;
    __shared__ int s_f32;
    // total ~94.3KB > 80KB -> 1 WG/CU (ticket scheme requirement)

    const int tid  = threadIdx.x;
    const int wave = tid >> 6;
    const int lane = tid & 63;
    const int kg   = wave >> 1;      // 0 = K-low (front), 1 = K-high (back)
    const int cg   = wave & 1;       // col-half: cols cg*16..+15
    const int m    = lane & 15;
    const int quad = lane >> 4;

    // ---- identify XCD, claim per-XCD CU slot ----
    if (tid == 0) {
        unsigned xcc;
        asm volatile("s_getreg_b32 %0, hwreg(HW_REG_XCC_ID, 0, 4)" : "=s"(xcc));
        xcc &= 7u;
        unsigned slot = l2_atomic_add(tickets + xcc * 16, 1u);
        s_xcd = xcc;
        s_slot = slot & 31u;
        s_f32 = 0;
        jc = 0u;
    }
    __syncthreads();
    { // runtime dtype detection on rec_w raw bits
        float v = bf2f(((const u16*)recwv)[tid]);
        if (!(v >= -1.0f && v <= 1.0f)) s_f32 = 1;
    }
    __syncthreads();
    const bool isf32 = (s_f32 != 0);
    const int xcd  = (int)s_xcd;
    const int slot = (int)s_slot;
    const int b0   = xcd * XR;
    const int j0   = slot * CC;
    const int dt   = slot & 3;       // dec tile: out cols 16dt..+15
    unsigned* mbX = mboxes + (size_t)xcd * 32 * 2 * MBL;
    unsigned* mbW = mbX + (slot * 2 + kg) * MBL;   // this wave's 16 poll words
    const int pg = slot >> 4, pi = slot & 15;      // publish word coords

    // ---- stage weights: PASS 1 = rec tiles + enc tails (68 ksg) ----
    for (int idx = tid; idx < 68 * 64; idx += NT) {
        int ksg = idx >> 6, l = idx & 63, n = l & 15, q = l >> 4;
        int tile = (ksg < 34) ? 0 : 1;
        int ksl  = ksg - 34 * tile;
        int j = j0 + (tile << 4) + n;
        bf16x8 v;
        if (!isf32) {
            const u16* src = (ksl < 32) ? (const u16*)recwv + (size_t)j * HD + ksl * 32 + q * 8
                                        : (const u16*)encwv + (size_t)j * NI + (ksl - 32) * 32 + q * 8;
            v = *(const bf16x8*)src;
        } else {
            const float* src = (ksl < 32) ? (const float*)recwv + (size_t)j * HD + ksl * 32 + q * 8
                                          : (const float*)encwv + (size_t)j * NI + (ksl - 32) * 32 + q * 8;
            #pragma unroll
            for (int i = 0; i < 8; ++i) v[i] = (short)f2bf(src[i]);
        }
        *(bf16x8*)&WB[idx * 8] = v;
    }
    __syncthreads();
    bf16x8 Breg[16];     // rec: tile cg, k-steps kg*16..+15
    #pragma unroll
    for (int ks = 0; ks < 16; ++ks)
        Breg[ks] = *(const bf16x8*)&WB[((cg * 34 + kg * 16 + ks) * 64 + lane) * 8];
    bf16x8 Ereg[2] = {};
    if (kg == 0) {       // enc tails for tile cg (front only)
        Ereg[0] = *(const bf16x8*)&WB[((cg * 34 + 32) * 64 + lane) * 8];
        Ereg[1] = *(const bf16x8*)&WB[((cg * 34 + 33) * 64 + lane) * 8];
    }
    __syncthreads();
    // ---- PASS 2 = fgt tiles (64 ksg) ----
    for (int idx = tid; idx < 64 * 64; idx += NT) {
        int ksg = idx >> 6, l = idx & 63, n = l & 15, q = l >> 4;
        int tile = ksg >> 5, ksl = ksg & 31;
        int j = j0 + (tile << 4) + n;
        bf16x8 v;
        if (!isf32) {
            v = *(const bf16x8*)((const u16*)fgtwv + (size_t)j * HD + ksl * 32 + q * 8);
        } else {
            const float* src = (const float*)fgtwv + (size_t)j * HD + ksl * 32 + q * 8;
            #pragma unroll
            for (int i = 0; i < 8; ++i) v[i] = (short)f2bf(src[i]);
        }
        *(bf16x8*)&WB[idx * 8] = v;
    }
    __syncthreads();
    bf16x8 Freg[16];     // fgt: tile cg, k-steps kg*16..+15
    #pragma unroll
    for (int ks = 0; ks < 16; ++ks)
        Freg[ks] = *(const bf16x8*)&WB[((cg * 32 + kg * 16 + ks) * 64 + lane) * 8];

    bf16x8 dfr[8];       // dec B-frags: K-quarter kg*512 + cg*256
    {
        int o = 16 * dt + m;
        int kqb = kg * 512 + cg * 256;
        #pragma unroll
        for (int ks = 0; ks < 8; ++ks) {
            int kb = kqb + ks * 32 + quad * 8;
            if (!isf32) dfr[ks] = *(const bf16x8*)((const u16*)decwv + (size_t)o * HD + kb);
            else {
                const float* src = (const float*)decwv + (size_t)o * HD + kb;
                #pragma unroll
                for (int i = 0; i < 8; ++i) dfr[ks][i] = (short)f2bf(src[i]);
            }
        }
    }
    if (tid < 16) decbS[tid] = ldv(decbv, 16 * dt + tid, isf32);

    // back waves own (col = j0 + cg*16 + m, rows quad*4..+3); h state in regs
    const int mycol = j0 + cg * 16 + m;
    float encb_r = 0.f;
    float hst[4] = {0.f, 0.f, 0.f, 0.f};
    if (kg == 1) {
        encb_r = ldv(encbv, mycol, isf32);
        float h0v = ldv(hinitwv, mycol, isf32) + ldv(hinitbv, mycol, isf32);
        #pragma unroll
        for (int r = 0; r < 4; ++r) {
            hst[r] = h0v;
            h0buf[(size_t)(b0 + quad * 4 + r) * HD + mycol] = f2bf(h0v);
        }
    }
    __syncthreads();                 // h0 stores drained (vmcnt in syncthreads)
    if (tid < 32)                    // publish h_0: value 1
        l2_atomic_swap_nr(mbX + (tid * 2 + pg) * MBL + pi, 1u);

    // x prefetch (front waves, one step ahead)
    bf16x8 xp0 = {}, xp1 = {};
    f32x4 xr0 = {}, xr1 = {}, xr2 = {}, xr3 = {};
    if (kg == 0) {
        size_t xb = (size_t)(b0 + m) * (TS * NI) + 0 * NI + quad * 8;
        if (!isf32) {
            xp0 = *(const bf16x8*)((const u16*)xv + xb);
            xp1 = *(const bf16x8*)((const u16*)xv + xb + 32);
        } else {
            const float* xp = (const float*)xv + xb;
            xr0 = *(const f32x4*)xp;        xr1 = *(const f32x4*)(xp + 4);
            xr2 = *(const f32x4*)(xp + 32); xr3 = *(const f32x4*)(xp + 36);
        }
    }

    // ---- recurrence: ONE barrier per step ----
    for (int t = 0; t < TS; ++t) {
        const int pp = t & 1;
        f32x4 acc0 = (f32x4){0.f, 0.f, 0.f, 0.f};   // rec (+enc on front)
        f32x4 acc1 = (f32x4){0.f, 0.f, 0.f, 0.f};   // fgt
        f32x4 dacc = (f32x4){0.f, 0.f, 0.f, 0.f};   // dec partial

        if (kg == 0) {   // enc MFMA with prefetched x
            bf16x8 xf0, xf1;
            if (!isf32) { xf0 = xp0; xf1 = xp1; }
            else {
                #pragma unroll
                for (int i = 0; i < 4; ++i) {
                    xf0[i] = (short)f2bf(xr0[i]); xf0[i + 4] = (short)f2bf(xr1[i]);
                    xf1[i] = (short)f2bf(xr2[i]); xf1[i + 4] = (short)f2bf(xr3[i]);
                }
            }
            acc0 = __builtin_amdgcn_mfma_f32_16x16x32_bf16(xf0, Ereg[0], acc0, 0, 0, 0);
            acc0 = __builtin_amdgcn_mfma_f32_16x16x32_bf16(xf1, Ereg[1], acc0, 0, 0, 0);
        }

        // poll this wave's 16 producer flags (one 64B line; R2 transport)
        {
            const unsigned target = (unsigned)(t + 1);
            for (;;) {
                unsigned v = target;
                if (lane < 16) v = l2_atomic_add(mbW + lane, 0u);
                if (__all((int)(v >= target))) break;
            }
        }

        const u16* cur = (t & 1) ? h1buf : h0buf;
        u16*       nxt = (t & 1) ? h0buf : h1buf;

        bf16x8 a[16];
        load_a16(cur + (size_t)(b0 + m) * HD + kg * 512 + quad * 8, a);

        if (kg == 0) {   // next step's x prefetch
            int tn = (t + 1 < TS) ? t + 1 : t;
            size_t xb = (size_t)(b0 + m) * (TS * NI) + (size_t)tn * NI + quad * 8;
            if (!isf32) {
                xp0 = *(const bf16x8*)((const u16*)xv + xb);
                xp1 = *(const bf16x8*)((const u16*)xv + xb + 32);
            } else {
                const float* xp = (const float*)xv + xb;
                xr0 = *(const f32x4*)xp;        xr1 = *(const f32x4*)(xp + 4);
                xr2 = *(const f32x4*)(xp + 32); xr3 = *(const f32x4*)(xp + 36);
            }
        }

        #pragma unroll
        for (int ks = 0; ks < 16; ++ks) {
            acc0 = __builtin_amdgcn_mfma_f32_16x16x32_bf16(a[ks], Breg[ks], acc0, 0, 0, 0);
            acc1 = __builtin_amdgcn_mfma_f32_16x16x32_bf16(a[ks], Freg[ks], acc1, 0, 0, 0);
        }
        // dec partial reuses loaded A-frags (dec K-quarter = cg-half of K-half)
        if (cg == 0) {
            #pragma unroll
            for (int ks = 0; ks < 8; ++ks)
                dacc = __builtin_amdgcn_mfma_f32_16x16x32_bf16(a[ks], dfr[ks], dacc, 0, 0, 0);
        } else {
            #pragma unroll
            for (int ks = 0; ks < 8; ++ks)
                dacc = __builtin_amdgcn_mfma_f32_16x16x32_bf16(a[8 + ks], dfr[ks], dacc, 0, 0, 0);
        }

        // C-layout: col = lane&15 (=m), row = quad*4 + reg
        if (kg == 0) {   // front: partials to LDS
            #pragma unroll
            for (int r = 0; r < 4; ++r) {
                recP[pp][cg][quad * 4 + r][m] = acc0[r];
                fgtP[pp][cg][quad * 4 + r][m] = acc1[r];
            }
        }
        {
            const int kq = kg * 2 + cg;
            #pragma unroll
            for (int r = 0; r < 4; ++r)
                decP[pp][kq][quad * 4 + r][m] = dacc[r];
        }
        __syncthreads();             // the ONE barrier: partials(t) complete

        if (kg == 1) {
            // elementwise in registers (K-high acc + K-low partial from LDS)
            #pragma unroll
            for (int r = 0; r < 4; ++r) {
                int row = quad * 4 + r;
                float pr = acc0[r] + recP[pp][cg][row][m] + encb_r;
                float pf = acc1[r] + fgtP[pp][cg][row][m];
                float fg = 1.0f / (1.0f + __expf(-pf));
                float hn = pr / (1.0f + fabsf(pr));
                hst[r] = hst[r] + fg * (hn - hst[r]);
                nxt[(size_t)(b0 + row) * HD + mycol] = f2bf(hst[r]);
            }
            asm volatile("s_waitcnt vmcnt(0)" ::: "memory");   // h stores L2-acked
            // LDS 2-join: the LAST back wave to drain publishes (no barrier2)
            int old = 0;
            if (lane == 0) old = (int)atomicAdd(&jc, 1u);
            old = __shfl(old, 0);
            if (old == 2 * t + 1 && lane < 32)
                l2_atomic_swap_nr(mbX + (lane * 2 + pg) * MBL + pi, (unsigned)(t + 2));
            // decode h_t -> out[t-1] (post-publish, off the h chain)
            if (slot < 4 && cg == 0 && t > 0) {
                #pragma unroll
                for (int e = 0; e < 4; ++e) {
                    int idx = lane * 4 + e, row = idx >> 4, col = idx & 15;
                    float o = decbS[col];
                    #pragma unroll
                    for (int kq = 0; kq < 4; ++kq) o += decP[pp][kq][row][col];
                    size_t oi = (size_t)(t - 1) * (BS * NO) + (size_t)(b0 + row) * NO + 16 * dt + col;
                    if (isf32) ((float*)outv)[oi] = o; else ((u16*)outv)[oi] = f2bf(o);
                }
            }
        }
    }

    // ---- epilogue: out[511] = decode(h_512); final hidden ----
    {
        {   // poll for h_512 (value TS+1)
            const unsigned target = (unsigned)(TS + 1);
            for (;;) {
                unsigned v = target;
                if (lane < 16) v = l2_atomic_add(mbW + lane, 0u);
                if (__all((int)(v >= target))) break;
            }
        }
        bf16x8 ad[8];
        load_a_frags(h0buf + (size_t)(b0 + m) * HD + kg * 512 + cg * 256 + quad * 8, ad);
        f32x4 dc = (f32x4){0.f, 0.f, 0.f, 0.f};
        #pragma unroll
        for (int ks = 0; ks < 8; ++ks)
            dc = __builtin_amdgcn_mfma_f32_16x16x32_bf16(ad[ks], dfr[ks], dc, 0, 0, 0);
        const int kq = kg * 2 + cg;
        #pragma unroll
        for (int r = 0; r < 4; ++r)
            decP[0][kq][quad * 4 + r][m] = dc[r];
        __syncthreads();
        if (slot < 4 && wave == 2) {
            #pragma unroll
            for (int e = 0; e < 4; ++e) {
                int idx = lane * 4 + e, row = idx >> 4, col = idx & 15;
                float o = decbS[col];
                #pragma unroll
                for (int kqq = 0; kqq < 4; ++kqq) o += decP[0][kqq][row][col];
                size_t oi = (size_t)511 * (BS * NO) + (size_t)(b0 + row) * NO + 16 * dt + col;
                if (isf32) ((float*)outv)[oi] = o; else ((u16*)outv)[oi] = f2bf(o);
            }
        }
        if (kg == 1) {   // final hidden straight from registers
            #pragma unroll
            for (int r = 0; r < 4; ++r) {
                size_t oi = (size_t)TS * BS * NO + (size_t)(b0 + quad * 4 + r) * HD + mycol;
                if (isf32) ((float*)outv)[oi] = hst[r]; else ((u16*)outv)[oi] = f2bf(hst[r]);
            }
        }
    }
}

extern "C" void kernel_launch(void* const* d_in, const int* in_sizes, int n_in,
                              void* d_out, int out_size, void* d_ws, size_t ws_size,
                              hipStream_t stream) {
    (void)in_sizes; (void)n_in; (void)out_size; (void)ws_size;
    const void* xv       = d_in[0];
    const void* encwv    = d_in[1];
    const void* encbv    = d_in[2];
    const void* recwv    = d_in[3];
    const void* fgtwv    = d_in[4];
    const void* decwv    = d_in[5];
    const void* decbv    = d_in[6];
    const void* hinitwv  = d_in[7];
    const void* hinitbv  = d_in[8];
    void* outv = d_out;

    unsigned* tickets = (unsigned*)d_ws;                       // 8 x 64B-stride
    unsigned* mboxes  = (unsigned*)((char*)d_ws + 4096);       // 8 x 32 x 2 x 64B = 32KB
    u16* h0buf = (u16*)((char*)d_ws + 524288);
    u16* h1buf = h0buf + (size_t)BS * HD;

    // zero tickets + mailboxes each launch (ws is re-poisoned to 0xAA)
    hipMemsetAsync(d_ws, 0, 4096 + 8 * 32 * 2 * MBL * 4, stream);

    void* args[] = { (void*)&xv, (void*)&encwv, (void*)&encbv, (void*)&recwv,
                     (void*)&fgtwv, (void*)&decwv, (void*)&decbv,
                     (void*)&hinitwv, (void*)&hinitbv,
                     (void*)&outv, (void*)&h0buf, (void*)&h1buf,
                     (void*)&tickets, (void*)&mboxes };
    // NEVER ignore the cooperative-launch return code.
    hipError_t err = hipLaunchCooperativeKernel((void*)arnn_xcd, dim3(NWG), dim3(NT), args, 0, stream);
    if (err != hipSuccess) {
        hipLaunchKernelGGL(arnn_xcd, dim3(NWG), dim3(NT), 0, stream,
                           xv, encwv, encbv, recwv, fgtwv, decwv, decbv,
                           hinitwv, hinitbv, outv, h0buf, h1buf, tickets, mboxes);
    }
}

// Round 11
// 1404.115 us; speedup vs baseline: 1.5133x; 1.5133x over previous
//
#include <hip/hip_runtime.h>

typedef unsigned short u16;

#define NWG 256
#define NT  256
#define TS  512
#define HD  1024
#define BS  128
#define NI  64
#define NO  64
#define XR  16      // batch rows per XCD
#define CC  32      // hidden cols per CU
#define RCP 17      // redC padded row stride

typedef __attribute__((ext_vector_type(8))) short bf16x8;
typedef __attribute__((ext_vector_type(4))) float f32x4;

__device__ __forceinline__ float bf2f(u16 u) {
    union { unsigned int i; float f; } v; v.i = ((unsigned int)u) << 16; return v.f;
}
__device__ __forceinline__ u16 f2bf(float f) {
    union { float fl; unsigned int i; } v; v.fl = f;
    unsigned int x = v.i;
    return (u16)((x + 0x7fffu + ((x >> 16) & 1u)) >> 16);  // RNE, finite inputs
}
__device__ __forceinline__ float ldv(const void* p, size_t i, bool isf32) {
    return isf32 ? ((const float*)p)[i] : bf2f(((const u16*)p)[i]);
}

// L2-executed atomic returning old value (sc0 = return-old).
// SESSION LEDGER (rounds 0-10): this transport -- fire-and-forget atomic swap
// publish (32/CU/step, one writer per word) + per-wave 8-lane atomic-add(0)
// poll on a private 64B line -- is the measured optimum. Proven facts:
//  R3: polls MUST be atomics (plain sc0-load spin never observes peer stores).
//  R1: plain-store publish + atomic poll bounces lines L2<->HBM (+240MB).
//  R5: flag-op count is the currency (~30-40B memory-side write per swap; 4x
//      ops -> +464MB traffic and congestion).
//  R8: poll bank layout is irrelevant (cost == memory-side RTT regardless).
//  R7: added concurrency (chains/waves sharing SIMDs) interferes, not overlaps.
//  R9: keep per-wave A-load at 8 frags and the poll set at 8 producers.
//  R6/R10: ticket-ordered CU-subset sync groups break correctness (cause not
//      auditable from source) -- do not split the XCD domain.
__device__ __forceinline__ unsigned l2_atomic_add(unsigned* p, unsigned v) {
    unsigned old;
    asm volatile("global_atomic_add %0, %1, %2, off sc0\n\t"
                 "s_waitcnt vmcnt(0)"
                 : "=&v"(old) : "v"(p), "v"(v) : "memory");
    return old;
}
// Fire-and-forget atomic SWAP publish. Single writer per word => no RMW
// accumulation at the coherence point.
__device__ __forceinline__ void l2_atomic_swap_nr(unsigned* p, unsigned v) {
    asm volatile("global_atomic_swap %0, %1, off" :: "v"(p), "v"(v) : "memory");
}

// 8 A-fragments (one K-quarter) via sc0 loads (L1 bypass -> XCD L2, where peer
// CUs' write-through stores live). Proven correct for *data* across sessions.
__device__ __forceinline__ void load_a_frags(const u16* ap, bf16x8* a) {
    asm volatile(
        "global_load_dwordx4 %0, %8, off sc0\n\t"
        "global_load_dwordx4 %1, %8, off offset:64 sc0\n\t"
        "global_load_dwordx4 %2, %8, off offset:128 sc0\n\t"
        "global_load_dwordx4 %3, %8, off offset:192 sc0\n\t"
        "global_load_dwordx4 %4, %8, off offset:256 sc0\n\t"
        "global_load_dwordx4 %5, %8, off offset:320 sc0\n\t"
        "global_load_dwordx4 %6, %8, off offset:384 sc0\n\t"
        "global_load_dwordx4 %7, %8, off offset:448 sc0\n\t"
        "s_waitcnt vmcnt(0)"
        : "=&v"(a[0]), "=&v"(a[1]), "=&v"(a[2]), "=&v"(a[3]),
          "=&v"(a[4]), "=&v"(a[5]), "=&v"(a[6]), "=&v"(a[7])
        : "v"(ap) : "memory");
}

// Mailbox layout: mb[xcd][consumer(32)][wave(4)][producer(8)] u32: each
// (consumer,wave) owns a private 64B line with the flags of the 8 producers
// its K-quarter depends on (wave w <- slots 8w..8w+7). Producer slot s
// publishes h_t by swapping (t+1) into word mb[c][s>>3][s&7] for every
// consumer c. value v >= t+1 <=> h_t published. WAR safety of the h ping-pong:
// a CU stores h_{t+1} only after all its waves (joined at the redC barrier)
// observed h_t from all 32 producers, and producing h_t implies that producer
// finished reading h_{t-1}. (Measured-best configuration: 1417us.)
#define MBL 16      // u32 words per (consumer,wave) line (64B)

// LDS ~157KB -> exactly 1 WG/CU (required by the per-XCD ticket scheme).
__global__ __launch_bounds__(NT)
void arnn_xcd(const void* __restrict__ xv,
              const void* __restrict__ encwv,
              const void* __restrict__ encbv,
              const void* __restrict__ recwv,
              const void* __restrict__ fgtwv,
              const void* __restrict__ decwv,
              const void* __restrict__ decbv,
              const void* __restrict__ hinitwv,
              const void* __restrict__ hinitbv,
              void* __restrict__ outv,
              u16* __restrict__ h0buf,
              u16* __restrict__ h1buf,
              unsigned* __restrict__ tickets,
              unsigned* __restrict__ mboxes)
{
    // WB: staging for register fragment pull (also pins LDS -> 1 WG/CU).
    __shared__ short WB[132 * 64 * 8];          // 135168 B
    __shared__ float redC[4 * 5 * 16 * RCP];    // 21760 B: [kq][tile(4=dec)][row][col]
    __shared__ unsigned s_xcd, s_slot;
    __shared__ int s_f32;

    const int tid  = threadIdx.x;
    const int wave = tid >> 6;
    const int lane = tid & 63;
    const int m    = lane & 15;      // C row / A row (batch-local)
    const int quad = lane >> 4;      // k-subblock within K=32

    // ---- identify XCD, claim per-XCD CU slot ----
    if (tid == 0) {
        unsigned xcc;
        asm volatile("s_getreg_b32 %0, hwreg(HW_REG_XCC_ID, 0, 4)" : "=s"(xcc));
        xcc &= 7u;
        unsigned slot = l2_atomic_add(tickets + xcc * 16, 1u);
        s_xcd = xcc;
        s_slot = slot & 31u;
        s_f32 = 0;
    }
    __syncthreads();
    { // runtime dtype detection on rec_w raw bits
        float v = bf2f(((const u16*)recwv)[tid]);
        if (!(v >= -1.0f && v <= 1.0f)) s_f32 = 1;
    }
    __syncthreads();
    const bool isf32 = (s_f32 != 0);
    const int xcd  = (int)s_xcd;
    const int slot = (int)s_slot;
    const int b0   = xcd * XR;       // this XCD's batch rows
    const int j0   = slot * CC;      // this CU's hidden cols
    const int dt   = slot & 3;       // dec tile: out cols 16dt..16dt+15
    unsigned* mbX   = mboxes + (size_t)xcd * 32 * 4 * MBL;      // XCD's flag block
    unsigned* mbW   = mbX + (slot * 4 + wave) * MBL;            // this wave's 8 flags
    // producer-side publish target word (per consumer c, computed in loop):
    const int pw = (slot >> 3), pi = (slot & 7);

    // ---- stage weights into LDS in B-frag order ----
    for (int idx = tid; idx < 132 * 64; idx += NT) {
        int ksg = idx >> 6, l = idx & 63, n = l & 15, q = l >> 4;
        int tile, ksl;
        if (ksg < 34)       { tile = 0; ksl = ksg; }
        else if (ksg < 68)  { tile = 1; ksl = ksg - 34; }
        else if (ksg < 100) { tile = 2; ksl = ksg - 68; }
        else                { tile = 3; ksl = ksg - 100; }
        int j = j0 + ((tile & 1) << 4) + n;
        bf16x8 v;
        if (!isf32) {
            const u16* src;
            if (tile < 2) src = (ksl < 32) ? (const u16*)recwv + (size_t)j * HD + ksl * 32 + q * 8
                                           : (const u16*)encwv + (size_t)j * NI + (ksl - 32) * 32 + q * 8;
            else          src = (const u16*)fgtwv + (size_t)j * HD + ksl * 32 + q * 8;
            v = *(const bf16x8*)src;
        } else {
            const float* src;
            if (tile < 2) src = (ksl < 32) ? (const float*)recwv + (size_t)j * HD + ksl * 32 + q * 8
                                           : (const float*)encwv + (size_t)j * NI + (ksl - 32) * 32 + q * 8;
            else          src = (const float*)fgtwv + (size_t)j * HD + ksl * 32 + q * 8;
            #pragma unroll
            for (int i = 0; i < 8; ++i) v[i] = (short)f2bf(src[i]);
        }
        *(bf16x8*)&WB[idx * 8] = v;
    }
    __syncthreads();     // WB fully staged before register pull

    // ---- ALL B-fragments register-resident (1 wave/SIMD -> big VGPR budget).
    bf16x8 Breg[2][8];   // rec tiles 0,1 for this wave's K-quarter
    bf16x8 Freg[2][8];   // fgt tiles 2,3 for this wave's K-quarter
    #pragma unroll
    for (int ks = 0; ks < 8; ++ks) {
        int kb = wave * 8 + ks;
        Breg[0][ks] = *(const bf16x8*)&WB[((0   + kb) * 64 + lane) * 8];
        Breg[1][ks] = *(const bf16x8*)&WB[((34  + kb) * 64 + lane) * 8];
        Freg[0][ks] = *(const bf16x8*)&WB[((68  + kb) * 64 + lane) * 8];
        Freg[1][ks] = *(const bf16x8*)&WB[((100 + kb) * 64 + lane) * 8];
    }
    bf16x8 Ereg[2];      // enc-tail B-frags (waves 0,1 only)
    if (wave < 2) {
        Ereg[0] = *(const bf16x8*)&WB[((32 + wave) * 64 + lane) * 8];
        Ereg[1] = *(const bf16x8*)&WB[((34 + 32 + wave) * 64 + lane) * 8];
    }
    bf16x8 dfr[8];       // dec B-frags for this wave's K-quarter
    {
        int o = 16 * dt + m;         // out column
        #pragma unroll
        for (int ks = 0; ks < 8; ++ks) {
            int kb = wave * 256 + ks * 32 + quad * 8;
            if (!isf32) dfr[ks] = *(const bf16x8*)((const u16*)decwv + (size_t)o * HD + kb);
            else {
                const float* src = (const float*)decwv + (size_t)o * HD + kb;
                #pragma unroll
                for (int i = 0; i < 8; ++i) dfr[ks][i] = (short)f2bf(src[i]);
            }
        }
    }
    // per-thread scalars; h state lives in registers (2 elems/thread: rows er, er+8)
    const int er = tid >> 5, ec = tid & 31;                  // (row, col) of elem 0
    float encb_r = ldv(encbv, j0 + ec, isf32);
    float decb_r = ldv(decbv, 16 * dt + (tid & 15), isf32);
    float h0v = ldv(hinitwv, j0 + ec, isf32) + ldv(hinitbv, j0 + ec, isf32);
    float hstA = h0v, hstB = h0v;                            // rows er / er+8
    h0buf[(size_t)(b0 + er    ) * HD + j0 + ec] = f2bf(h0v);
    h0buf[(size_t)(b0 + er + 8) * HD + j0 + ec] = f2bf(h0v);
    __syncthreads();                             // h0 stores acked by L2 (vmcnt(0))
    if (tid < 32)                                // publish h_0: value 1
        l2_atomic_swap_nr(mbX + (tid * 4 + pw) * MBL + pi, 1u);

    // ---- recurrence ----
    for (int t = 0; t < TS; ++t) {
        f32x4 acc[5];
        #pragma unroll
        for (int tt = 0; tt < 5; ++tt) acc[tt] = (f32x4){0.f, 0.f, 0.f, 0.f};

        // enc contribution BEFORE the wait (x is read-only input)
        if (wave < 2) {
            bf16x8 xf;
            size_t xb = (size_t)(b0 + m) * (TS * NI) + (size_t)t * NI + wave * 32 + quad * 8;
            if (!isf32) xf = *(const bf16x8*)((const u16*)xv + xb);
            else {
                const float* xp = (const float*)xv + xb;
                #pragma unroll
                for (int i = 0; i < 8; ++i) xf[i] = (short)f2bf(xp[i]);
            }
            acc[0] = __builtin_amdgcn_mfma_f32_16x16x32_bf16(xf, Ereg[0], acc[0], 0, 0, 0);
            acc[1] = __builtin_amdgcn_mfma_f32_16x16x32_bf16(xf, Ereg[1], acc[1], 0, 0, 0);
        }

        // Per-wave poll: one 8-lane ATOMIC gather of this wave's OWN producer
        // flags (private 64B line; proven transport).
        {
            const unsigned target = (unsigned)(t + 1);
            for (;;) {
                unsigned v = target;
                if (lane < 8) v = l2_atomic_add(mbW + lane, 0u);
                if (__all((int)(v >= target))) break;
            }
        }

        const u16* cur = (t & 1) ? h1buf : h0buf;
        u16*       nxt = (t & 1) ? h0buf : h1buf;

        bf16x8 a[8];
        load_a_frags(cur + (size_t)(b0 + m) * HD + wave * 256 + quad * 8, a);

        #pragma unroll
        for (int ks = 0; ks < 8; ++ks) {
            acc[0] = __builtin_amdgcn_mfma_f32_16x16x32_bf16(a[ks], Breg[0][ks], acc[0], 0, 0, 0);
            acc[1] = __builtin_amdgcn_mfma_f32_16x16x32_bf16(a[ks], Breg[1][ks], acc[1], 0, 0, 0);
            acc[2] = __builtin_amdgcn_mfma_f32_16x16x32_bf16(a[ks], Freg[0][ks], acc[2], 0, 0, 0);
            acc[3] = __builtin_amdgcn_mfma_f32_16x16x32_bf16(a[ks], Freg[1][ks], acc[3], 0, 0, 0);
            acc[4] = __builtin_amdgcn_mfma_f32_16x16x32_bf16(a[ks], dfr[ks],     acc[4], 0, 0, 0);
        }

        // C-layout 16x16: col = lane&15, row = quad*4 + reg
        #pragma unroll
        for (int tt = 0; tt < 5; ++tt) {
            #pragma unroll
            for (int r = 0; r < 4; ++r)
                redC[((wave * 5 + tt) * 16 + quad * 4 + r) * RCP + m] = acc[tt][r];
        }
        __syncthreads();

        // elementwise FIRST (h stores issue early; their L2 acks overlap the
        // decode below, so the pre-publish barrier waits less)
        {
            const int tl = ec >> 4, col = ec & 15;
            float pr0 = encb_r, pf0 = 0.f, pr1 = encb_r, pf1 = 0.f;
            #pragma unroll
            for (int kq = 0; kq < 4; ++kq) {
                pr0 += redC[((kq * 5 + tl) * 16 + er) * RCP + col];
                pf0 += redC[((kq * 5 + 2 + tl) * 16 + er) * RCP + col];
                pr1 += redC[((kq * 5 + tl) * 16 + er + 8) * RCP + col];
                pf1 += redC[((kq * 5 + 2 + tl) * 16 + er + 8) * RCP + col];
            }
            float fg0 = 1.0f / (1.0f + __expf(-pf0));
            float hn0 = pr0 / (1.0f + fabsf(pr0));
            hstA = hstA + fg0 * (hn0 - hstA);
            nxt[(size_t)(b0 + er) * HD + j0 + ec] = f2bf(hstA);
            float fg1 = 1.0f / (1.0f + __expf(-pf1));
            float hn1 = pr1 / (1.0f + fabsf(pr1));
            hstB = hstB + fg1 * (hn1 - hstB);
            nxt[(size_t)(b0 + er + 8) * HD + j0 + ec] = f2bf(hstB);
        }
        // decode h_t -> out[t-1]
        if (slot < 4 && t > 0) {
            int r = tid >> 4, col = tid & 15;
            float o = decb_r;
            #pragma unroll
            for (int kq = 0; kq < 4; ++kq)
                o += redC[((kq * 5 + 4) * 16 + r) * RCP + col];
            size_t oi = (size_t)(t - 1) * (BS * NO) + (size_t)(b0 + r) * NO + 16 * dt + col;
            if (isf32) ((float*)outv)[oi] = o; else ((u16*)outv)[oi] = f2bf(o);
        }
        __syncthreads();                       // all waves' h (and out) stores acked by L2
        if (tid < 32)                          // publish h_{t+1}: value t+2
            l2_atomic_swap_nr(mbX + (tid * 4 + pw) * MBL + pi, (unsigned)(t + 2));
    }

    // ---- epilogue: out[511] = decode(h_512); final hidden ----
    if (slot < 4) {
        {   // per-wave poll for h_512 (value TS+1)
            const unsigned target = (unsigned)(TS + 1);
            for (;;) {
                unsigned v = target;
                if (lane < 8) v = l2_atomic_add(mbW + lane, 0u);
                if (__all((int)(v >= target))) break;
            }
        }
        bf16x8 a[8];
        load_a_frags(h0buf + (size_t)(b0 + m) * HD + wave * 256 + quad * 8, a);
        f32x4 ac = (f32x4){0.f, 0.f, 0.f, 0.f};
        #pragma unroll
        for (int ks = 0; ks < 8; ++ks)
            ac = __builtin_amdgcn_mfma_f32_16x16x32_bf16(a[ks], dfr[ks], ac, 0, 0, 0);
        #pragma unroll
        for (int r = 0; r < 4; ++r)
            redC[((wave * 5 + 4) * 16 + quad * 4 + r) * RCP + m] = ac[r];
        __syncthreads();
        {
            int r = tid >> 4, col = tid & 15;
            float o = decb_r;
            #pragma unroll
            for (int kq = 0; kq < 4; ++kq)
                o += redC[((kq * 5 + 4) * 16 + r) * RCP + col];
            size_t oi = (size_t)511 * (BS * NO) + (size_t)(b0 + r) * NO + 16 * dt + col;
            if (isf32) ((float*)outv)[oi] = o; else ((u16*)outv)[oi] = f2bf(o);
        }
    }
    {   // final hidden straight from registers
        size_t oi0 = (size_t)TS * BS * NO + (size_t)(b0 + er) * HD + j0 + ec;
        size_t oi1 = (size_t)TS * BS * NO + (size_t)(b0 + er + 8) * HD + j0 + ec;
        if (isf32) { ((float*)outv)[oi0] = hstA; ((float*)outv)[oi1] = hstB; }
        else       { ((u16*)outv)[oi0] = f2bf(hstA); ((u16*)outv)[oi1] = f2bf(hstB); }
    }
}

extern "C" void kernel_launch(void* const* d_in, const int* in_sizes, int n_in,
                              void* d_out, int out_size, void* d_ws, size_t ws_size,
                              hipStream_t stream) {
    (void)in_sizes; (void)n_in; (void)out_size; (void)ws_size;
    const void* xv       = d_in[0];
    const void* encwv    = d_in[1];
    const void* encbv    = d_in[2];
    const void* recwv    = d_in[3];
    const void* fgtwv    = d_in[4];
    const void* decwv    = d_in[5];
    const void* decbv    = d_in[6];
    const void* hinitwv  = d_in[7];
    const void* hinitbv  = d_in[8];
    void* outv = d_out;

    unsigned* tickets = (unsigned*)d_ws;                       // 8 x 64B-stride
    unsigned* mboxes  = (unsigned*)((char*)d_ws + 4096);       // 8 x 32 x 4 x 64B = 64KB
    u16* h0buf = (u16*)((char*)d_ws + 524288);
    u16* h1buf = h0buf + (size_t)BS * HD;

    // zero tickets + mailboxes each launch (ws is re-poisoned to 0xAA)
    hipMemsetAsync(d_ws, 0, 4096 + 8 * 32 * 4 * MBL * 4, stream);

    void* args[] = { (void*)&xv, (void*)&encwv, (void*)&encbv, (void*)&recwv,
                     (void*)&fgtwv, (void*)&decwv, (void*)&decbv,
                     (void*)&hinitwv, (void*)&hinitbv,
                     (void*)&outv, (void*)&h0buf, (void*)&h1buf,
                     (void*)&tickets, (void*)&mboxes };
    // NEVER ignore the cooperative-launch return code.
    hipError_t err = hipLaunchCooperativeKernel((void*)arnn_xcd, dim3(NWG), dim3(NT), args, 0, stream);
    if (err != hipSuccess) {
        hipLaunchKernelGGL(arnn_xcd, dim3(NWG), dim3(NT), 0, stream,
                           xv, encwv, encbv, recwv, fgtwv, decwv, decbv,
                           hinitwv, hinitbv, outv, h0buf, h1buf, tickets, mboxes);
    }
}